// Round 10
// baseline (195.272 us; speedup 1.0000x reference)
//
#include <hip/hip_runtime.h>

typedef __attribute__((ext_vector_type(8))) short bf16x8;
typedef __attribute__((ext_vector_type(4))) short bf16x4;
typedef __attribute__((ext_vector_type(16))) float f32x16;

#define VQ_MAGIC 0x5AFE3A7Bu

__device__ __forceinline__ bool lex_lt(float av, int ai, float bv, int bi) {
  return av < bv || (av == bv && ai < bi);
}

// round-to-nearest-even fp32 -> bf16 (low 16 bits)
__device__ __forceinline__ unsigned bf16_rne(float v) {
  unsigned u = __float_as_uint(v);
  return (u + 0x7fffu + ((u >> 16) & 1u)) >> 16;
}

// packed RNE bf16 convert of (a,b) -> one 32-bit word (low=a, high=b)
__device__ __forceinline__ unsigned pk_bf16(float a, float b) {
  return bf16_rne(a) | (bf16_rne(b) << 16);
}

// ---------------------------------------------------------------------------
// vq_fused: ONE launch, 512 blocks (2/CU co-resident by launch-bounds
// arithmetic), 512 threads.
// Producers: blocks 0..63 convert the codebook to k-major bf16-split planes
//   (4 elems/thread) + wT; blocks 64..67 compute e2 in fp64. Each producer
//   block then release-stores flags[bid] = MAGIC (NO atomicRMW — R3's
//   failure; 68 flags spread over lines — no hot line).
// All blocks: stage own x tile to LDS (overlaps producer pre-work).
// Wait: ONE wave per block polls the 68 flags with relaxed agent loads at
//   s_sleep(8) cadence (~3 loads/sweep/block — no fabric flood; R4's
//   failure was 262K spinners). MAGIC compare makes poisoned workspace safe
//   without a memset dispatch.
// Then: R9's verified main pipeline, byte-identical (lockstep chunk order =
//   L1-resident wtil slice; both-sides LDS swizzle; pipelined half-2 stage).
// ---------------------------------------------------------------------------
__global__ __launch_bounds__(512, 4) void vq_fused(
    const float* __restrict__ x, const float* __restrict__ w,
    float* __restrict__ e2g, short* __restrict__ wtil,
    float* __restrict__ wT, unsigned* __restrict__ flags,
    float* __restrict__ out, float* __restrict__ arg_out) {
  __shared__ __align__(16) char arena[76800];
  short* xh   = (short*)arena;                 // [64][256] swizzled, 32 KB
  short* xl   = (short*)(arena + 32768);       // 32 KB
  float* e2s  = (float*)(arena + 65536);       // 2 KB
  float* tv1  = (float*)(arena + 67584);       // [8][64]
  float* tv2  = (float*)(arena + 69632);
  int*   ti1  = (int*)(arena + 71680);
  int*   ti2  = (int*)(arena + 73728);
  int*   p1S  = (int*)(arena + 75776);         // [64]
  int*   p2S  = (int*)(arena + 76032);
  int*   needS= (int*)(arena + 76288);
  int*   rpickS=(int*)(arena + 76544);
  // gather phase: gbuf[d*68 + pos], 256x68 floats = 69632 B
  // (aliases xh/xl/e2s/tv which are dead; p1S..rpickS at >=75776 survive)
  float* gbuf = (float*)arena;

  const int tid = threadIdx.x;
  const int bid = blockIdx.x;

  // ---- Phase A: producers (blocks 0..67)
  if (bid < 64) {
    int gid = bid * 512 + tid;  // 0..32767
    int n  = gid & 511;
    int kq = gid >> 9;          // 0..63
    int kg = kq >> 1;
    int jb = (kq & 1) << 2;     // 0 or 4
    bf16x4 hv, lv;
    float vv[4];
#pragma unroll
    for (int j = 0; j < 4; ++j) {
      float v = w[(kg * 8 + jb + j) * 512 + n];
      vv[j] = v;
      unsigned h = bf16_rne(v);
      float hf = __uint_as_float(h << 16);
      unsigned l = bf16_rne(v - hf);
      hv[j] = (short)h;
      lv[j] = (short)l;
    }
    short* dst = wtil + ((size_t)kg * 512 + n) * 8 + jb;
    *(bf16x4*)dst = hv;
    *(bf16x4*)(dst + 131072) = lv;
    if (wT) {
      float* p = wT + (size_t)n * 256 + kg * 8 + jb;
      *(float4*)p = make_float4(vv[0], vv[1], vv[2], vv[3]);
    }
  } else if (bid < 68) {
    int t = (bid - 64) * 512 + tid;  // 0..2047
    int k = t >> 2;
    int part = t & 3;
    double s = 0.0;
#pragma unroll 8
    for (int d = part * 64; d < part * 64 + 64; ++d) {
      double v = (double)w[d * 512 + k];
      s = fma(v, v, s);
    }
    s += __shfl_xor(s, 1);
    s += __shfl_xor(s, 2);
    if (part == 0) e2g[k] = (float)s;
  }
  if (bid < 68) {
    __threadfence();          // each thread's writes visible device-wide
    __syncthreads();          // whole block done
    if (tid == 0)
      __hip_atomic_store(&flags[bid], VQ_MAGIC, __ATOMIC_RELEASE,
                         __HIP_MEMORY_SCOPE_AGENT);
  }

  const int b  = bid >> 4;
  const int n0 = (bid & 15) << 6;              // 64 positions
  const float* xbase = x + (size_t)b * 262144 + n0;

  const int n2  = tid & 31;      // position-pair (2 pos each)
  const int kgh = tid >> 5;      // 0..15: kg within a 16-group half

  // convert+write 2 positions (m = 2*n2, 2*n2+1) for kg group kg8
  auto cw2 = [&](int kg8, const float2* v) {
#pragma unroll
    for (int i = 0; i < 2; ++i) {
      int m = (n2 << 1) + i;
      union { int w4[4]; bf16x8 v8; } H, L;
#pragma unroll
      for (int jj = 0; jj < 4; ++jj) {
        float a = (i == 0) ? v[2*jj].x   : v[2*jj].y;
        float c = (i == 0) ? v[2*jj+1].x : v[2*jj+1].y;
        unsigned hu = pk_bf16(a, c);
        float haf = __uint_as_float(hu << 16);
        float hcf = __uint_as_float(hu & 0xffff0000u);
        unsigned lu = pk_bf16(a - haf, c - hcf);
        H.w4[jj] = (int)hu;
        L.w4[jj] = (int)lu;
      }
      int slot = kg8 ^ (m & 7) ^ ((m >> 3) & 7);
      int off = (m << 8) + (slot << 3);
      *(bf16x8*)&xh[off] = H.v8;
      *(bf16x8*)&xl[off] = L.v8;
    }
  };

  // ---- Phase B: stage half 1: dims 0..127 (kg 0..15)
  {
    float2 v[8];
#pragma unroll
    for (int j = 0; j < 8; ++j)
      v[j] = *(const float2*)(xbase + (size_t)(kgh * 8 + j) * 1024 + (n2 << 1));
    cw2(kgh, v);
  }
  __syncthreads();

  // issue dim-128..255 x loads early — they fly during the flag wait
  float2 vx[8];
#pragma unroll
  for (int j = 0; j < 8; ++j)
    vx[j] = *(const float2*)(xbase + (size_t)((kgh + 16) * 8 + j) * 1024 + (n2 << 1));

  // ---- Phase C: wait for all 68 producer flags (wave 0 only)
  if (tid < 64) {
    long spins = 0;
    for (;;) {
      unsigned f1 = __hip_atomic_load(&flags[tid], __ATOMIC_RELAXED,
                                      __HIP_MEMORY_SCOPE_AGENT);
      unsigned f2 = (tid < 4)
          ? __hip_atomic_load(&flags[64 + tid], __ATOMIC_RELAXED,
                              __HIP_MEMORY_SCOPE_AGENT)
          : VQ_MAGIC;
      if (__all(f1 == VQ_MAGIC && f2 == VQ_MAGIC)) break;
      __builtin_amdgcn_s_sleep(8);
      if (++spins > (1L << 19)) break;   // ~0.1 s valve: loud failure, no hang
    }
  }
  __syncthreads();
  __threadfence();          // acquire for wtil/e2/wT
  e2s[tid] = e2g[tid];
  __syncthreads();

  const int lane = tid & 63;
  const int wv   = tid >> 6;     // wave 0..7: codes [wv*64, wv*64+64)
  const int ln   = lane & 31;
  const int half = lane >> 5;
  const int wb   = wv << 6;

  f32x16 acc[2][2];   // [code-tile ct][pos-tile pt]
#pragma unroll
  for (int ct = 0; ct < 2; ++ct)
#pragma unroll
    for (int pt = 0; pt < 2; ++pt)
#pragma unroll
      for (int r = 0; r < 16; ++r) acc[ct][pt][r] = 0.f;

  const int asw = (ln & 7) ^ (ln >> 3);   // read swizzle (matches write)
  const int abase = ln << 8;

  int bofs[2];
#pragma unroll
  for (int ct = 0; ct < 2; ++ct) bofs[ct] = (wb + (ct << 5) + ln) << 3;

  bf16x8 pch[2], pcl[2];
#pragma unroll
  for (int ct = 0; ct < 2; ++ct) {
    const short* p = wtil + (half << 12) + bofs[ct];
    pch[ct] = *(const bf16x8*)p;
    pcl[ct] = *(const bf16x8*)(p + 131072);
  }

  auto kstep = [&](int ch) {
    const int kg = (ch << 1) + half;
    const int ao = abase + ((kg ^ asw) << 3);
    bf16x8 xf[2], xg[2];
#pragma unroll
    for (int pt = 0; pt < 2; ++pt) {
      const int ap = (ao + (pt << 13)) ^ (pt << 5);  // pos+32 flips slot bit 2
      xf[pt] = *(const bf16x8*)&xh[ap];
      xg[pt] = *(const bf16x8*)&xl[ap];
    }
    bf16x8 cfh[2], cfl[2];
#pragma unroll
    for (int ct = 0; ct < 2; ++ct) { cfh[ct] = pch[ct]; cfl[ct] = pcl[ct]; }
    if (ch < 15) {
      const int kgn = ((ch + 1) << 1) + half;
#pragma unroll
      for (int ct = 0; ct < 2; ++ct) {
        const short* p = wtil + (kgn << 12) + bofs[ct];
        pch[ct] = *(const bf16x8*)p;
        pcl[ct] = *(const bf16x8*)(p + 131072);
      }
    }
#pragma unroll
    for (int ct = 0; ct < 2; ++ct)
#pragma unroll
      for (int pt = 0; pt < 2; ++pt) {
        acc[ct][pt] = __builtin_amdgcn_mfma_f32_32x32x16_bf16(cfh[ct], xf[pt], acc[ct][pt], 0, 0, 0);
        acc[ct][pt] = __builtin_amdgcn_mfma_f32_32x32x16_bf16(cfh[ct], xg[pt], acc[ct][pt], 0, 0, 0);
        acc[ct][pt] = __builtin_amdgcn_mfma_f32_32x32x16_bf16(cfl[ct], xf[pt], acc[ct][pt], 0, 0, 0);
      }
  };

  // ---- pipelined: ksteps 0..3 (kg 0..7), convert+write kg16..31 (unread
  //      until kstep 8), ksteps 4..7, barrier, ksteps 8..15.
  kstep(0); kstep(1); kstep(2); kstep(3);
  cw2(kgh + 16, vx);
  kstep(4); kstep(5); kstep(6); kstep(7);
  __syncthreads();
  kstep(8);  kstep(9);  kstep(10); kstep(11);
  kstep(12); kstep(13); kstep(14); kstep(15);

  // ---- epilogue: per-lane register scan (codes in regs), one xor-32 merge
  float e2r[2][16];
#pragma unroll
  for (int ct = 0; ct < 2; ++ct)
#pragma unroll
    for (int r = 0; r < 16; ++r)
      e2r[ct][r] = e2s[wb + (ct << 5) + (r & 3) + ((r >> 2) << 3) + (half << 2)];

#pragma unroll
  for (int pt = 0; pt < 2; ++pt) {
    float v1 = 3.4e38f, v2 = 3.4e38f;
    int i1 = 0x7fffffff, i2 = 0x7fffffff;
#pragma unroll
    for (int ct = 0; ct < 2; ++ct) {
#pragma unroll
      for (int r = 0; r < 16; ++r) {
        int k = wb + (ct << 5) + (r & 3) + ((r >> 2) << 3) + (half << 2);
        float s = fmaf(-2.f, acc[ct][pt][r], e2r[ct][r]);
        if (lex_lt(s, k, v1, i1)) { v2 = v1; i2 = i1; v1 = s; i1 = k; }
        else if (lex_lt(s, k, v2, i2)) { v2 = s; i2 = k; }
      }
    }
    {
      float ov1 = __shfl_xor(v1, 32);
      int   oi1 = __shfl_xor(i1, 32);
      float ov2 = __shfl_xor(v2, 32);
      int   oi2 = __shfl_xor(i2, 32);
      bool aFirst = lex_lt(v1, i1, ov1, oi1);
      float nv1 = aFirst ? v1 : ov1;  int ni1 = aFirst ? i1 : oi1;
      float cv  = aFirst ? ov1 : v1;  int ci  = aFirst ? oi1 : i1;
      float sv  = aFirst ? v2 : ov2;  int si  = aFirst ? i2 : oi2;
      bool cFirst = lex_lt(cv, ci, sv, si);
      v1 = nv1; i1 = ni1;
      v2 = cFirst ? cv : sv; i2 = cFirst ? ci : si;
    }
    if (half == 0) {
      int s = (wv << 6) + (pt << 5) + ln;
      tv1[s] = v1; ti1[s] = i1; tv2[s] = v2; ti2[s] = i2;
    }
  }
  __syncthreads();

  // ---- cross-wave merge (tid<64), publish top-2 + need flag
  if (tid < 64) {
    int row = tid;
    float v1 = 3.4e38f, v2 = 3.4e38f;
    int i1 = 0x7fffffff, i2 = 0x7fffffff;
#pragma unroll
    for (int wvv = 0; wvv < 8; ++wvv) {
      int s = (wvv << 6) + row;
      float a1 = tv1[s]; int ai = ti1[s];
      float a2 = tv2[s]; int bi = ti2[s];
      if (lex_lt(a1, ai, v1, i1)) { v2 = v1; i2 = i1; v1 = a1; i1 = ai; }
      else if (lex_lt(a1, ai, v2, i2)) { v2 = a1; i2 = ai; }
      if (lex_lt(a2, bi, v1, i1)) { v2 = v1; i2 = i1; v1 = a2; i1 = bi; }
      else if (lex_lt(a2, bi, v2, i2)) { v2 = a2; i2 = bi; }
    }
    p1S[row] = i1; p2S[row] = i2;
    needS[row] = (v2 - v1 < 0.01f) ? 1 : 0;   // >3x worst-case split-GEMM jitter
    rpickS[row] = i1;
  }
  __syncthreads();

  // ---- parallel fp64 refinement: wave wv handles rows wv, wv+8, ...
  for (int t = 0; t < 8; ++t) {
    int row = (t << 3) + wv;
    if (needS[row]) {
      int i1 = p1S[row], i2 = p2S[row];
      const float* xp = x + (size_t)b * 262144 + n0 + row;
      double s1 = 0.0, s2 = 0.0;
      int k0 = lane << 2;
#pragma unroll
      for (int i = 0; i < 4; ++i) {
        int k = k0 + i;
        double xv = (double)xp[(size_t)k * 1024];
        double w1 = (double)w[k * 512 + i1];
        double w2 = (double)w[k * 512 + i2];
        double t1 = xv - w1, t2 = xv - w2;
        s1 = fma(t1, t1, s1);
        s2 = fma(t2, t2, s2);
      }
#pragma unroll
      for (int off = 32; off >= 1; off >>= 1) {
        s1 += __shfl_xor(s1, off);
        s2 += __shfl_xor(s2, off);
      }
      if (lane == 0 && (s2 < s1 || (s2 == s1 && i2 < i1))) rpickS[row] = i2;
    }
  }
  __syncthreads();

  // ---- write argmin + gather via transposed LDS bounce
  if (tid < 64) arg_out[b * 1024 + n0 + tid] = (float)rpickS[tid];

  if (wT) {
    {
      const int pos  = tid >> 3;        // 64 positions, 8 threads each
      const int dseg = tid & 7;
      const float* wrow = wT + (size_t)rpickS[pos] * 256;
#pragma unroll
      for (int j = 0; j < 8; ++j) {
        int d0 = (j << 5) + (dseg << 2);
        float4 v = *(const float4*)(wrow + d0);
        gbuf[(d0 + 0) * 68 + pos] = v.x;
        gbuf[(d0 + 1) * 68 + pos] = v.y;
        gbuf[(d0 + 2) * 68 + pos] = v.z;
        gbuf[(d0 + 3) * 68 + pos] = v.w;
      }
    }
    __syncthreads();
    {
      const int nn0 = (tid & 15) << 2;
      const int d0g = tid >> 4;          // 0..31
      float* obase = out + (size_t)b * 262144 + n0 + nn0;
#pragma unroll
      for (int dg = 0; dg < 8; ++dg) {
        int d = d0g + (dg << 5);
        float4 o = *(const float4*)&gbuf[d * 68 + nn0];
        *(float4*)(obase + (size_t)d * 1024) = o;
      }
    }
  } else {
    const int nn0 = (tid & 15) << 2;
    const int d0g = tid >> 4;
    int pk0 = rpickS[nn0], pk1 = rpickS[nn0 + 1], pk2 = rpickS[nn0 + 2], pk3 = rpickS[nn0 + 3];
    float* obase = out + (size_t)b * 262144 + n0 + nn0;
#pragma unroll
    for (int dg = 0; dg < 8; ++dg) {
      int d = d0g + (dg << 5);
      const float* wr = w + d * 512;
      float4 o = make_float4(wr[pk0], wr[pk1], wr[pk2], wr[pk3]);
      *(float4*)(obase + (size_t)d * 1024) = o;
    }
  }
}

// ---------------------------------------------------------------------------
extern "C" void kernel_launch(void* const* d_in, const int* in_sizes, int n_in,
                              void* d_out, int out_size, void* d_ws, size_t ws_size,
                              hipStream_t stream) {
  const float* x = (const float*)d_in[0];
  const float* w = (const float*)d_in[1];
  float* out  = (float*)d_out;
  float* argf = out + 8388608;
  float* e2   = (float*)d_ws;                       // 2048 B
  short* wtil = (short*)((char*)d_ws + 2048);       // 512 KB
  size_t need = 2048 + 524288 + 524288 + 272;
  float* wT   = (ws_size >= ((size_t)1 << 21) + 272)
                  ? (float*)((char*)d_ws + 2048 + 524288) : nullptr;
  unsigned* flags = (unsigned*)((char*)d_ws + (1 << 21));  // 68 words
  (void)need;

  vq_fused<<<512, 512, 0, stream>>>(x, w, e2, wtil, wT, flags, out, argf);
}

// Round 11
// 115.116 us; speedup vs baseline: 1.6963x; 1.6963x over previous
//
#include <hip/hip_runtime.h>

typedef __attribute__((ext_vector_type(8))) short bf16x8;
typedef __attribute__((ext_vector_type(16))) float f32x16;

__device__ __forceinline__ bool lex_lt(float av, int ai, float bv, int bi) {
  return av < bv || (av == bv && ai < bi);
}

// round-to-nearest-even fp32 -> bf16 (low 16 bits)
__device__ __forceinline__ unsigned bf16_rne(float v) {
  unsigned u = __float_as_uint(v);
  return (u + 0x7fffu + ((u >> 16) & 1u)) >> 16;
}

// packed RNE bf16 convert of (a,b) -> one 32-bit word (low=a, high=b)
__device__ __forceinline__ unsigned pk_bf16(float a, float b) {
  return bf16_rne(a) | (bf16_rne(b) << 16);
}

// ---------------------------------------------------------------------------
// vq_pre: blocks 0..63 build k-major bf16-split codebook planes
// wh[kg][n][8], wl[kg][n][8] + exact fp32 transposed codebook wT[n][d];
// blocks 64..71: e2[k] in fp64 (4-way d-split per k).
// NOTE (session): fusing this into vq_main via a grid-wide sync was tried 3
// ways (atomic-RMW barrier, distributed-poll barrier, per-block flags +
// single-wave poll); all cost 60-90 us on MI355X's non-coherent-L2 fabric
// vs the ~27 us this separate launch costs. Keep the two-kernel structure.
// ---------------------------------------------------------------------------
__global__ __launch_bounds__(256) void vq_pre(
    const float* __restrict__ w, float* __restrict__ e2,
    short* __restrict__ wtil, float* __restrict__ wT) {
  int blk = blockIdx.x;
  if (blk < 64) {
    int gid = blk * 256 + threadIdx.x;  // 16384 threads
    int n  = gid & 511;
    int kg = gid >> 9;
    bf16x8 hv, lv;
    float vv[8];
#pragma unroll
    for (int j = 0; j < 8; ++j) {
      float v = w[(kg * 8 + j) * 512 + n];
      vv[j] = v;
      unsigned h = bf16_rne(v);
      float hf = __uint_as_float(h << 16);
      unsigned l = bf16_rne(v - hf);
      hv[j] = (short)h;
      lv[j] = (short)l;
    }
    short* dst = wtil + (size_t)gid * 8;   // (kg*512 + n)*8
    *(bf16x8*)dst = hv;
    *(bf16x8*)(dst + 131072) = lv;
    if (wT) {
      float* p = wT + (size_t)n * 256 + kg * 8;
      *(float4*)p       = make_float4(vv[0], vv[1], vv[2], vv[3]);
      *(float4*)(p + 4) = make_float4(vv[4], vv[5], vv[6], vv[7]);
    }
  } else {
    int t = (blk - 64) * 256 + threadIdx.x;  // 0..2047
    int k = t >> 2;
    int part = t & 3;
    double s = 0.0;
#pragma unroll 8
    for (int d = part * 64; d < part * 64 + 64; ++d) {
      double v = (double)w[d * 512 + k];
      s = fma(v, v, s);
    }
    s += __shfl_xor(s, 1);
    s += __shfl_xor(s, 2);
    if (part == 0) e2[k] = (float)s;
  }
}

// ---------------------------------------------------------------------------
// vq_main: 512 blocks (2/CU), 512 threads (8 waves).
// Block = 64 positions x 512 codes; wave owns 64 codes (ct=2, x-frag reuse).
// P=64 is the measured optimum (P-sweep 32/64/128: codebook L2 stream scales
// 1/P, but P=128 forces 1 block/CU phase serialization).
// Lockstep chunk order (deliberate: one chunk's 32 KB wtil slice is exactly
// L1-sized; R7's stagger experiment proved de-phasing costs ~20 us via L1
// thrash). Both-sides LDS swizzle: write slot = kgp ^ (m&7) ^ ((m>>3)&7),
// read asw = (ln&7) ^ (ln>>3) with pt=1 ^32 — staging writes at the b128
// floor (conflicts 2.75M -> 1.97M, measured).
// ---------------------------------------------------------------------------
__global__ __launch_bounds__(512, 4) void vq_main(
    const float* __restrict__ x, const float* __restrict__ w,
    const float* __restrict__ e2g, const short* __restrict__ wtil,
    const float* __restrict__ wT,
    float* __restrict__ out, float* __restrict__ arg_out) {
  __shared__ __align__(16) char arena[76800];
  short* xh   = (short*)arena;                 // [64][256] swizzled, 32 KB
  short* xl   = (short*)(arena + 32768);       // 32 KB
  float* e2s  = (float*)(arena + 65536);       // 2 KB
  float* tv1  = (float*)(arena + 67584);       // [8][64]
  float* tv2  = (float*)(arena + 69632);
  int*   ti1  = (int*)(arena + 71680);
  int*   ti2  = (int*)(arena + 73728);
  int*   p1S  = (int*)(arena + 75776);         // [64]
  int*   p2S  = (int*)(arena + 76032);
  int*   needS= (int*)(arena + 76288);
  int*   rpickS=(int*)(arena + 76544);
  // gather phase: gbuf[d*68 + pos], 256x68 floats = 69632 B
  // (aliases xh/xl/e2s/tv which are dead; p1S..rpickS at >=75776 survive)
  float* gbuf = (float*)arena;

  const int tid = threadIdx.x;
  const int b  = blockIdx.x >> 4;
  const int n0 = (blockIdx.x & 15) << 6;       // 64 positions
  const float* xbase = x + (size_t)b * 262144 + n0;

  // ---- stage all 256 dims in one pass
  {
    e2s[tid] = e2g[tid];
    const int n4  = tid & 15;      // position-quad (4 pos each)
    const int kgp = tid >> 4;      // 0..31: all kg groups
    float4 v[8];
#pragma unroll
    for (int j = 0; j < 8; ++j)
      v[j] = *(const float4*)(xbase + (size_t)(kgp * 8 + j) * 1024 + (n4 << 2));
#pragma unroll
    for (int i = 0; i < 4; ++i) {
      int m = (n4 << 2) + i;
      union { int w4[4]; bf16x8 v8; } H, L;
#pragma unroll
      for (int jj = 0; jj < 4; ++jj) {
        float a = (i == 0) ? v[2*jj].x : (i == 1) ? v[2*jj].y : (i == 2) ? v[2*jj].z : v[2*jj].w;
        float c = (i == 0) ? v[2*jj+1].x : (i == 1) ? v[2*jj+1].y : (i == 2) ? v[2*jj+1].z : v[2*jj+1].w;
        unsigned hu = pk_bf16(a, c);
        float haf = __uint_as_float(hu << 16);
        float hcf = __uint_as_float(hu & 0xffff0000u);
        unsigned lu = pk_bf16(a - haf, c - hcf);
        H.w4[jj] = (int)hu;
        L.w4[jj] = (int)lu;
      }
      int slot = kgp ^ (m & 7) ^ ((m >> 3) & 7);
      int off = (m << 8) + (slot << 3);
      *(bf16x8*)&xh[off] = H.v8;
      *(bf16x8*)&xl[off] = L.v8;
    }
  }
  __syncthreads();

  const int lane = tid & 63;
  const int wv   = tid >> 6;     // wave 0..7: codes [wv*64, wv*64+64)
  const int ln   = lane & 31;
  const int half = lane >> 5;
  const int wb   = wv << 6;

  f32x16 acc[2][2];   // [code-tile ct][pos-tile pt]
#pragma unroll
  for (int ct = 0; ct < 2; ++ct)
#pragma unroll
    for (int pt = 0; pt < 2; ++pt)
#pragma unroll
      for (int r = 0; r < 16; ++r) acc[ct][pt][r] = 0.f;

  const int asw = (ln & 7) ^ (ln >> 3);   // read swizzle (matches write)
  const int abase = ln << 8;

  int bofs[2];
#pragma unroll
  for (int ct = 0; ct < 2; ++ct) bofs[ct] = (wb + (ct << 5) + ln) << 3;

  bf16x8 pch[2], pcl[2];
#pragma unroll
  for (int ct = 0; ct < 2; ++ct) {
    const short* p = wtil + (half << 12) + bofs[ct];
    pch[ct] = *(const bf16x8*)p;
    pcl[ct] = *(const bf16x8*)(p + 131072);
  }

  auto kstep = [&](int ch) {
    const int kg = (ch << 1) + half;
    const int ao = abase + ((kg ^ asw) << 3);
    bf16x8 xf[2], xg[2];
#pragma unroll
    for (int pt = 0; pt < 2; ++pt) {
      const int ap = (ao + (pt << 13)) ^ (pt << 5);  // pos+32 flips slot bit 2
      xf[pt] = *(const bf16x8*)&xh[ap];
      xg[pt] = *(const bf16x8*)&xl[ap];
    }
    bf16x8 cfh[2], cfl[2];
#pragma unroll
    for (int ct = 0; ct < 2; ++ct) { cfh[ct] = pch[ct]; cfl[ct] = pcl[ct]; }
    if (ch < 15) {
      const int kgn = ((ch + 1) << 1) + half;
#pragma unroll
      for (int ct = 0; ct < 2; ++ct) {
        const short* p = wtil + (kgn << 12) + bofs[ct];
        pch[ct] = *(const bf16x8*)p;
        pcl[ct] = *(const bf16x8*)(p + 131072);
      }
    }
#pragma unroll
    for (int ct = 0; ct < 2; ++ct)
#pragma unroll
      for (int pt = 0; pt < 2; ++pt) {
        acc[ct][pt] = __builtin_amdgcn_mfma_f32_32x32x16_bf16(cfh[ct], xf[pt], acc[ct][pt], 0, 0, 0);
        acc[ct][pt] = __builtin_amdgcn_mfma_f32_32x32x16_bf16(cfh[ct], xg[pt], acc[ct][pt], 0, 0, 0);
        acc[ct][pt] = __builtin_amdgcn_mfma_f32_32x32x16_bf16(cfl[ct], xf[pt], acc[ct][pt], 0, 0, 0);
      }
  };

  kstep(0);  kstep(1);  kstep(2);  kstep(3);
  kstep(4);  kstep(5);  kstep(6);  kstep(7);
  kstep(8);  kstep(9);  kstep(10); kstep(11);
  kstep(12); kstep(13); kstep(14); kstep(15);

  // ---- epilogue: per-lane register scan (codes in regs), one xor-32 merge
  float e2r[2][16];
#pragma unroll
  for (int ct = 0; ct < 2; ++ct)
#pragma unroll
    for (int r = 0; r < 16; ++r)
      e2r[ct][r] = e2s[wb + (ct << 5) + (r & 3) + ((r >> 2) << 3) + (half << 2)];

#pragma unroll
  for (int pt = 0; pt < 2; ++pt) {
    float v1 = 3.4e38f, v2 = 3.4e38f;
    int i1 = 0x7fffffff, i2 = 0x7fffffff;
#pragma unroll
    for (int ct = 0; ct < 2; ++ct) {
#pragma unroll
      for (int r = 0; r < 16; ++r) {
        int k = wb + (ct << 5) + (r & 3) + ((r >> 2) << 3) + (half << 2);
        float s = fmaf(-2.f, acc[ct][pt][r], e2r[ct][r]);
        if (lex_lt(s, k, v1, i1)) { v2 = v1; i2 = i1; v1 = s; i1 = k; }
        else if (lex_lt(s, k, v2, i2)) { v2 = s; i2 = k; }
      }
    }
    {
      float ov1 = __shfl_xor(v1, 32);
      int   oi1 = __shfl_xor(i1, 32);
      float ov2 = __shfl_xor(v2, 32);
      int   oi2 = __shfl_xor(i2, 32);
      bool aFirst = lex_lt(v1, i1, ov1, oi1);
      float nv1 = aFirst ? v1 : ov1;  int ni1 = aFirst ? i1 : oi1;
      float cv  = aFirst ? ov1 : v1;  int ci  = aFirst ? oi1 : i1;
      float sv  = aFirst ? v2 : ov2;  int si  = aFirst ? i2 : oi2;
      bool cFirst = lex_lt(cv, ci, sv, si);
      v1 = nv1; i1 = ni1;
      v2 = cFirst ? cv : sv; i2 = cFirst ? ci : si;
    }
    if (half == 0) {
      int s = (wv << 6) + (pt << 5) + ln;
      tv1[s] = v1; ti1[s] = i1; tv2[s] = v2; ti2[s] = i2;
    }
  }
  __syncthreads();

  // ---- cross-wave merge (tid<64), publish top-2 + need flag
  if (tid < 64) {
    int row = tid;
    float v1 = 3.4e38f, v2 = 3.4e38f;
    int i1 = 0x7fffffff, i2 = 0x7fffffff;
#pragma unroll
    for (int wvv = 0; wvv < 8; ++wvv) {
      int s = (wvv << 6) + row;
      float a1 = tv1[s]; int ai = ti1[s];
      float a2 = tv2[s]; int bi = ti2[s];
      if (lex_lt(a1, ai, v1, i1)) { v2 = v1; i2 = i1; v1 = a1; i1 = ai; }
      else if (lex_lt(a1, ai, v2, i2)) { v2 = a1; i2 = ai; }
      if (lex_lt(a2, bi, v1, i1)) { v2 = v1; i2 = i1; v1 = a2; i1 = bi; }
      else if (lex_lt(a2, bi, v2, i2)) { v2 = a2; i2 = bi; }
    }
    p1S[row] = i1; p2S[row] = i2;
    needS[row] = (v2 - v1 < 0.01f) ? 1 : 0;   // >3x worst-case split-GEMM jitter
    rpickS[row] = i1;
  }
  __syncthreads();

  // ---- parallel fp64 refinement: wave wv handles rows wv, wv+8, ...
  for (int t = 0; t < 8; ++t) {
    int row = (t << 3) + wv;
    if (needS[row]) {
      int i1 = p1S[row], i2 = p2S[row];
      const float* xp = x + (size_t)b * 262144 + n0 + row;
      double s1 = 0.0, s2 = 0.0;
      int k0 = lane << 2;
#pragma unroll
      for (int i = 0; i < 4; ++i) {
        int k = k0 + i;
        double xv = (double)xp[(size_t)k * 1024];
        double w1 = (double)w[k * 512 + i1];
        double w2 = (double)w[k * 512 + i2];
        double t1 = xv - w1, t2 = xv - w2;
        s1 = fma(t1, t1, s1);
        s2 = fma(t2, t2, s2);
      }
#pragma unroll
      for (int off = 32; off >= 1; off >>= 1) {
        s1 += __shfl_xor(s1, off);
        s2 += __shfl_xor(s2, off);
      }
      if (lane == 0 && (s2 < s1 || (s2 == s1 && i2 < i1))) rpickS[row] = i2;
    }
  }
  __syncthreads();

  // ---- write argmin + gather via transposed LDS bounce
  if (tid < 64) arg_out[b * 1024 + n0 + tid] = (float)rpickS[tid];

  if (wT) {
    {
      const int pos  = tid >> 3;        // 64 positions, 8 threads each
      const int dseg = tid & 7;
      const float* wrow = wT + (size_t)rpickS[pos] * 256;
#pragma unroll
      for (int j = 0; j < 8; ++j) {
        int d0 = (j << 5) + (dseg << 2);
        float4 v = *(const float4*)(wrow + d0);
        gbuf[(d0 + 0) * 68 + pos] = v.x;
        gbuf[(d0 + 1) * 68 + pos] = v.y;
        gbuf[(d0 + 2) * 68 + pos] = v.z;
        gbuf[(d0 + 3) * 68 + pos] = v.w;
      }
    }
    __syncthreads();
    {
      const int nn0 = (tid & 15) << 2;
      const int d0g = tid >> 4;          // 0..31
      float* obase = out + (size_t)b * 262144 + n0 + nn0;
#pragma unroll
      for (int dg = 0; dg < 8; ++dg) {
        int d = d0g + (dg << 5);
        float4 o = *(const float4*)&gbuf[d * 68 + nn0];
        *(float4*)(obase + (size_t)d * 1024) = o;
      }
    }
  } else {
    const int nn0 = (tid & 15) << 2;
    const int d0g = tid >> 4;
    int pk0 = rpickS[nn0], pk1 = rpickS[nn0 + 1], pk2 = rpickS[nn0 + 2], pk3 = rpickS[nn0 + 3];
    float* obase = out + (size_t)b * 262144 + n0 + nn0;
#pragma unroll
    for (int dg = 0; dg < 8; ++dg) {
      int d = d0g + (dg << 5);
      const float* wr = w + d * 512;
      float4 o = make_float4(wr[pk0], wr[pk1], wr[pk2], wr[pk3]);
      *(float4*)(obase + (size_t)d * 1024) = o;
    }
  }
}

// ---------------------------------------------------------------------------
extern "C" void kernel_launch(void* const* d_in, const int* in_sizes, int n_in,
                              void* d_out, int out_size, void* d_ws, size_t ws_size,
                              hipStream_t stream) {
  const float* x = (const float*)d_in[0];
  const float* w = (const float*)d_in[1];
  float* out  = (float*)d_out;
  float* argf = out + 8388608;
  float* e2   = (float*)d_ws;                       // 2048 B
  short* wtil = (short*)((char*)d_ws + 2048);       // 512 KB
  size_t need = 2048 + 524288 + 524288;
  float* wT   = (ws_size >= need) ? (float*)((char*)d_ws + 2048 + 524288) : nullptr;

  vq_pre<<<72, 256, 0, stream>>>(w, e2, wtil, wT);
  vq_main<<<512, 512, 0, stream>>>(x, w, e2, wtil, wT, out, argf);
}